// Round 5
// baseline (260.044 us; speedup 1.0000x reference)
//
#include <hip/hip_runtime.h>
#include <hip/hip_bf16.h>

#define BB 32
#define LL 196
#define DD 512
#define HH 8
#define DHH 64
#define BL (BB*LL)   // 6272
#define NPAD 6400    // 25 * 256 (padded GEMM dim for retrieve)
#define PVK 224      // padded m-dim for PV (7 * 32)
#define PSTR 236     // pr LDS stride (bf16)

typedef __bf16 bf16x8 __attribute__((ext_vector_type(8)));
typedef float f32x4 __attribute__((ext_vector_type(4)));

#define MFMA16(a,b,c) __builtin_amdgcn_mfma_f32_16x16x32_bf16((a),(b),(c),0,0,0)

#define GLOAD_LDS16(g, l) __builtin_amdgcn_global_load_lds( \
    (const __attribute__((address_space(1))) void*)(g), \
    (__attribute__((address_space(3))) void*)(l), 16, 0, 0)

static __device__ __forceinline__ bf16x8 pack8(float4 v0, float4 v1) {
  bf16x8 o;
  o[0] = (__bf16)v0.x; o[1] = (__bf16)v0.y; o[2] = (__bf16)v0.z; o[3] = (__bf16)v0.w;
  o[4] = (__bf16)v1.x; o[5] = (__bf16)v1.y; o[6] = (__bf16)v1.z; o[7] = (__bf16)v1.w;
  return o;
}

static __device__ __forceinline__ unsigned fkey(float f) {
  unsigned u = __float_as_uint(f);
  return u ^ ((unsigned)((int)u >> 31) | 0x80000000u);
}
static __device__ __forceinline__ float unkey(unsigned k) {
  unsigned u = (k & 0x80000000u) ? (k ^ 0x80000000u) : ~k;
  return __uint_as_float(u);
}

// ---------------------------------------------------------------------------
// f32 -> bf16 bulk convert: X (3 x 6272x512) and W (3 x 512x512)
// ---------------------------------------------------------------------------
__global__ __launch_bounds__(256) void cvt_kernel(
    const float* __restrict__ x0, const float* __restrict__ x1, const float* __restrict__ x2,
    const float* __restrict__ w0, const float* __restrict__ w1, const float* __restrict__ w2,
    __bf16* __restrict__ xb, __bf16* __restrict__ wb)
{
  const int z = blockIdx.y;
  const float* src; __bf16* dst; size_t i;
  if (blockIdx.x < 1568) {
    src = (z == 0) ? x0 : (z == 1) ? x1 : x2;
    dst = xb + (size_t)z * 3211264;
    i = (size_t)blockIdx.x * 256 + threadIdx.x;
  } else {
    src = (z == 0) ? w0 : (z == 1) ? w1 : w2;
    dst = wb + (size_t)z * 262144;
    i = (size_t)(blockIdx.x - 1568) * 256 + threadIdx.x;
  }
  const float4* s = (const float4*)(src + i * 8);
  float4 a = s[0], b = s[1];
  *(bf16x8*)(dst + i * 8) = pack8(a, b);
}

// ---------------------------------------------------------------------------
// Projection NT GEMM (bf16 in/out), 128x128 tile, single-buffer m97 structure
// grid (49, 4, 3), block 256
// ---------------------------------------------------------------------------
#define STAGE_PAIR(SA, SB, abase, bbase) do { \
  const __bf16* aB_ = (abase); const __bf16* bB_ = (bbase); \
  _Pragma("unroll") \
  for (int c_ = 0; c_ < 4; ++c_) { \
    const int p_ = c_ * 256 + tid; \
    GLOAD_LDS16(aB_ + (size_t)(p_ >> 3) * DD + swoff, &SA[p_ * 8]); \
  } \
  _Pragma("unroll") \
  for (int c_ = 0; c_ < 4; ++c_) { \
    const int p_ = c_ * 256 + tid; \
    GLOAD_LDS16(bB_ + (size_t)(p_ >> 3) * DD + swoff, &SB[p_ * 8]); \
  } \
} while (0)

#define COMPUTE_TILE(SA, SB) do { \
  _Pragma("unroll") \
  for (int kc_ = 0; kc_ < 2; ++kc_) { \
    const int q_ = (((kc_ * 4 + (lane >> 4)) ^ (lane & 7)) << 3); \
    bf16x8 af_[4], bf_[4]; \
    _Pragma("unroll") \
    for (int mt_ = 0; mt_ < 4; ++mt_) \
      af_[mt_] = *(const bf16x8*)&SA[(wr + mt_ * 16 + (lane & 15)) * 64 + q_]; \
    _Pragma("unroll") \
    for (int nt_ = 0; nt_ < 4; ++nt_) \
      bf_[nt_] = *(const bf16x8*)&SB[(wc + nt_ * 16 + (lane & 15)) * 64 + q_]; \
    _Pragma("unroll") \
    for (int mt_ = 0; mt_ < 4; ++mt_) \
      _Pragma("unroll") \
      for (int nt_ = 0; nt_ < 4; ++nt_) \
        acc[mt_][nt_] = MFMA16(af_[mt_], bf_[nt_], acc[mt_][nt_]); \
  } \
} while (0)

__global__ __launch_bounds__(256) void proj_gemm_kernel(
    const __bf16* __restrict__ xb, const __bf16* __restrict__ wb,
    const float* __restrict__ bq, const float* __restrict__ bk, const float* __restrict__ bv,
    __bf16* __restrict__ qp, __bf16* __restrict__ kp, __bf16* __restrict__ vp)
{
  __shared__ __bf16 sA[128 * 64];
  __shared__ __bf16 sB[128 * 64];

  const int z = blockIdx.z;
  const __bf16* A = xb + (size_t)z * 3211264;
  const __bf16* B = wb + (size_t)z * 262144;
  const float* bias = (z == 0) ? bq : (z == 1) ? bk : bv;
  __bf16* out = (z == 0) ? qp : (z == 1) ? kp : vp;

  const int tid = threadIdx.x;
  const int w = tid >> 6, lane = tid & 63;
  const int wr = (w >> 1) * 64, wc = (w & 1) * 64;
  const int bm = blockIdx.x * 128, bn = blockIdx.y * 128;
  const int swoff = ((tid & 7) ^ ((tid >> 3) & 7)) << 3;

  const __bf16* aP = A + (size_t)bm * DD;
  const __bf16* bP = B + (size_t)bn * DD;

  f32x4 acc[4][4] = {};

  #pragma unroll
  for (int kt = 0; kt < 8; ++kt) {
    STAGE_PAIR(sA, sB, aP + kt * 64, bP + kt * 64);
    __syncthreads();
    COMPUTE_TILE(sA, sB);
    __syncthreads();
  }

  #pragma unroll
  for (int mt = 0; mt < 4; ++mt)
    #pragma unroll
    for (int nt = 0; nt < 4; ++nt)
      #pragma unroll
      for (int rr = 0; rr < 4; ++rr) {
        const int row = bm + wr + mt * 16 + (lane >> 4) * 4 + rr;
        const int col = bn + wc + nt * 16 + (lane & 15);
        out[(size_t)row * DD + col] = (__bf16)(acc[mt][nt][rr] + bias[col]);
      }
}

// ---------------------------------------------------------------------------
// V transpose: vp[(bb*196+m)][h*64+d] -> vpT[(bb*8+h)*64+d][m] (m padded to 224)
// ---------------------------------------------------------------------------
__global__ __launch_bounds__(256) void transpose_v_kernel(
    const __bf16* __restrict__ vp, __bf16* __restrict__ vpT)
{
  __shared__ __bf16 sT[64][72];
  const int bbh = blockIdx.x;
  const int mt = blockIdx.y;
  const int bb = bbh >> 3, h = bbh & 7;
  const int tid = threadIdx.x;
  {
    const int r = tid >> 2, c0 = (tid & 3) * 16;
    const int m = mt * 64 + r;
    bf16x8 z = {};
    bf16x8 v0 = z, v1 = z;
    if (m < LL) {
      const bf16x8* src = (const bf16x8*)&vp[(size_t)(bb * LL + m) * DD + h * DHH + c0];
      v0 = src[0]; v1 = src[1];
    }
    *(bf16x8*)&sT[r][c0]     = v0;
    *(bf16x8*)&sT[r][c0 + 8] = v1;
  }
  __syncthreads();
  {
    const int d = tid >> 2, mc0 = (tid & 3) * 16;
    if (mt * 64 + mc0 < PVK) {
      bf16x8 o0, o1;
      #pragma unroll
      for (int j = 0; j < 8; ++j) { o0[j] = sT[mc0 + j][d]; o1[j] = sT[mc0 + 8 + j][d]; }
      __bf16* dst = vpT + (size_t)(bbh * 64 + d) * PVK + mt * 64 + mc0;
      *(bf16x8*)dst = o0;
      *(bf16x8*)(dst + 8) = o1;
    }
  }
}

// ---------------------------------------------------------------------------
// Retrieve: padded 6400x6400x512 NT GEMM, 256x256 tile, BK=32, 4-slot LDS ring,
// counted vmcnt (T3/T4) + swizzle (T2) + setprio (T5), fused segment-max epilogue.
// grid 625, block 512
// ---------------------------------------------------------------------------
#define STAGE_T(T) do { \
  char* la_ = ldsb + ((T) & 3) * 32768; \
  const __bf16* ga_ = aG + (T) * 32; \
  const __bf16* gb_ = bG + (T) * 32; \
  GLOAD_LDS16(ga_,            la_ + tid * 16); \
  GLOAD_LDS16(ga_ + 128 * DD, la_ + 8192 + tid * 16); \
  GLOAD_LDS16(gb_,            la_ + 16384 + tid * 16); \
  GLOAD_LDS16(gb_ + 128 * DD, la_ + 24576 + tid * 16); \
} while (0)

#define RITER(T, VM) do { \
  if ((T) + 3 < 16) { STAGE_T((T) + 3); } \
  asm volatile("s_waitcnt vmcnt(" #VM ")" ::: "memory"); \
  __builtin_amdgcn_s_barrier(); \
  { \
    const __bf16* lA_ = (const __bf16*)(ldsb + ((T) & 3) * 32768); \
    const __bf16* lB_ = lA_ + 8192; \
    bf16x8 bfr_[4]; \
    _Pragma("unroll") \
    for (int nt_ = 0; nt_ < 4; ++nt_) \
      bfr_[nt_] = *(const bf16x8*)&lB_[(wc + nt_ * 16 + (lane & 15)) * 32 + rswz]; \
    __builtin_amdgcn_s_setprio(1); \
    _Pragma("unroll") \
    for (int mt_ = 0; mt_ < 8; ++mt_) { \
      bf16x8 af_ = *(const bf16x8*)&lA_[(wr + mt_ * 16 + (lane & 15)) * 32 + rswz]; \
      _Pragma("unroll") \
      for (int nt_ = 0; nt_ < 4; ++nt_) \
        acc[mt_][nt_] = MFMA16(af_, bfr_[nt_], acc[mt_][nt_]); \
    } \
    __builtin_amdgcn_s_setprio(0); \
  } \
  __builtin_amdgcn_s_barrier(); \
} while (0)

__global__ __launch_bounds__(512, 2) void retrieve_kernel(
    const __bf16* __restrict__ qp, const __bf16* __restrict__ kp,
    unsigned* __restrict__ rmax, unsigned* __restrict__ cmax)
{
  __shared__ char ldsb[131072];   // 4 slots x (A 256x32 + B 256x32) bf16

  // bijective XCD chunking (625 = 8*78 + 1) then 5x5 supertile decode
  const int orig = blockIdx.x;
  const int xcd = orig & 7, idx = orig >> 3;
  const int wg = (xcd == 0) ? idx : (79 + (xcd - 1) * 78 + idx);
  const int st = wg / 25, wi = wg % 25;
  const int brow = ((st / 5) * 5 + wi / 5) * 256;
  const int bcol = ((st % 5) * 5 + wi % 5) * 256;

  const int tid = threadIdx.x;
  const int wid = tid >> 6, lane = tid & 63;
  const int wr = (wid >> 2) * 128, wc = (wid & 3) * 64;

  // staging: thread t covers row=tid>>2 (+128 for 2nd load), slot=tid&3;
  // source pre-swizzle slot' = slot ^ ((row ^ (row>>2)) & 3)
  const int sswz = (tid & 3) ^ ((tid >> 2) & 3) ^ ((tid >> 4) & 3);
  const __bf16* aG = qp + (size_t)(brow + (tid >> 2)) * DD + sswz * 8;
  const __bf16* bG = kp + (size_t)(bcol + (tid >> 2)) * DD + sswz * 8;

  // read swizzle (lane-constant): slot-read = g ^ ((row ^ row>>2)&3), row&3==lane&3
  const int rswz = ((lane >> 4) ^ (lane & 3) ^ ((lane >> 2) & 3)) << 3;

  f32x4 acc[8][4] = {};

  STAGE_T(0); STAGE_T(1); STAGE_T(2);

  RITER(0, 12);  RITER(1, 12);  RITER(2, 12);  RITER(3, 12);
  RITER(4, 12);  RITER(5, 12);  RITER(6, 12);  RITER(7, 12);
  RITER(8, 12);  RITER(9, 12);  RITER(10, 12); RITER(11, 12);
  RITER(12, 12); RITER(13, 8);  RITER(14, 4);  RITER(15, 0);

  const int wcol0 = bcol + wc;
  const int wrow0 = brow + wr;
  // Row-max per 196-col segment (t2v): rmax[b][grow]
  {
    const int b0 = wcol0 / LL;
    const int b1 = (wcol0 + 63) / LL;
    for (int b = b0; b <= b1 && b < BB; ++b) {
      const int lo = b * LL, hi = lo + LL;
      #pragma unroll
      for (int mt = 0; mt < 8; ++mt)
        #pragma unroll
        for (int rr = 0; rr < 4; ++rr) {
          float m = -3e38f;
          #pragma unroll
          for (int nt = 0; nt < 4; ++nt) {
            const int col = wcol0 + nt * 16 + (lane & 15);
            if (col >= lo && col < hi) m = fmaxf(m, acc[mt][nt][rr]);
          }
          m = fmaxf(m, __shfl_xor(m, 1));
          m = fmaxf(m, __shfl_xor(m, 2));
          m = fmaxf(m, __shfl_xor(m, 4));
          m = fmaxf(m, __shfl_xor(m, 8));
          if ((lane & 15) == 0) {
            const int grow = wrow0 + mt * 16 + (lane >> 4) * 4 + rr;
            if (grow < BL) atomicMax(&rmax[(size_t)b * BL + grow], fkey(m));
          }
        }
    }
  }
  // Col-max per 196-row segment (v2t): cmax[a][col]
  {
    const int a0 = wrow0 / LL;
    const int a1 = (wrow0 + 127) / LL;
    for (int a = a0; a <= a1 && a < BB; ++a) {
      const int lo = a * LL, hi = lo + LL;
      #pragma unroll
      for (int nt = 0; nt < 4; ++nt) {
        float cm = -3e38f;
        #pragma unroll
        for (int mt = 0; mt < 8; ++mt)
          #pragma unroll
          for (int rr = 0; rr < 4; ++rr) {
            const int grow = wrow0 + mt * 16 + (lane >> 4) * 4 + rr;
            if (grow >= lo && grow < hi) cm = fmaxf(cm, acc[mt][nt][rr]);
          }
        cm = fmaxf(cm, __shfl_xor(cm, 16));
        cm = fmaxf(cm, __shfl_xor(cm, 32));
        if (lane < 16) {
          const int col = wcol0 + nt * 16 + lane;
          if (col < BL) atomicMax(&cmax[(size_t)a * BL + col], fkey(cm));
        }
      }
    }
  }
}

// ---------------------------------------------------------------------------
// Fold rmax/cmax into logits. grid 256, block 256 (one wave per (a,b))
// ---------------------------------------------------------------------------
__global__ __launch_bounds__(256) void finish_kernel(
    const unsigned* __restrict__ rmax, const unsigned* __restrict__ cmax,
    const float* __restrict__ ls, float* __restrict__ out_logits)
{
  const int tid = threadIdx.x;
  const int w = tid >> 6, lane = tid & 63;
  const int pair = blockIdx.x * 4 + w;
  const int a = pair >> 5, b = pair & 31;
  float s = 0.f;
  #pragma unroll
  for (int k = 0; k < 4; ++k) {
    const int l = lane + k * 64;
    if (l < LL) {
      s += unkey(rmax[(size_t)b * BL + a * LL + l]);
      s += unkey(cmax[(size_t)a * BL + b * LL + l]);
    }
  }
  #pragma unroll
  for (int o = 1; o < 64; o <<= 1) s += __shfl_xor(s, o);
  if (lane == 0)
    out_logits[a * BB + b] = expf(ls[0]) * s * (0.5f / (float)LL);
}

// ---------------------------------------------------------------------------
// Self-attention: block = (bb, strip of 16 q-rows); 8 waves = 1 head each.
// grid (32, 13), block 512
// ---------------------------------------------------------------------------
__global__ __launch_bounds__(512) void attn_kernel(
    const __bf16* __restrict__ qp, const __bf16* __restrict__ kp,
    const __bf16* __restrict__ vpT, float* __restrict__ ctx,
    float* __restrict__ probs_out)
{
  __shared__ __bf16 pr[8][16][PSTR];

  const int bb = blockIdx.x;
  const int strip = blockIdx.y;
  const int tid = threadIdx.x;
  const int w = tid >> 6, lane = tid & 63;   // w == head
  const int h = w;
  const int row0 = strip * 16;

  for (int i = lane; i < 256; i += 64)
    pr[w][i >> 4][208 + (i & 15)] = (__bf16)0.f;

  const int arow = row0 + (lane & 15);
  const bool aval = arow < LL;

  bf16x8 aq[2];
  #pragma unroll
  for (int kc = 0; kc < 2; ++kc) {
    bf16x8 z = {};
    aq[kc] = aval
      ? *(const bf16x8*)&qp[(size_t)(bb * LL + arow) * DD + h * DHH + kc * 32 + (lane >> 4) * 8]
      : z;
  }
  f32x4 s[13] = {};
  __builtin_amdgcn_s_setprio(1);
  #pragma unroll
  for (int nt = 0; nt < 13; ++nt) {
    const int brow = nt * 16 + (lane & 15);
    #pragma unroll
    for (int kc = 0; kc < 2; ++kc) {
      bf16x8 bk = {};
      if (brow < LL)
        bk = *(const bf16x8*)&kp[(size_t)(bb * LL + brow) * DD + h * DHH + kc * 32 + (lane >> 4) * 8];
      s[nt] = MFMA16(aq[kc], bk, s[nt]);
    }
  }
  __builtin_amdgcn_s_setprio(0);

  const int colbase = lane & 15;
  #pragma unroll
  for (int nt = 0; nt < 13; ++nt) {
    const bool cv = (nt * 16 + colbase) < LL;
    #pragma unroll
    for (int rr = 0; rr < 4; ++rr)
      s[nt][rr] = cv ? s[nt][rr] * 0.125f : -1e30f;
  }
  float mx[4], dn[4];
  #pragma unroll
  for (int rr = 0; rr < 4; ++rr) {
    float m = s[0][rr];
    #pragma unroll
    for (int nt = 1; nt < 13; ++nt) m = fmaxf(m, s[nt][rr]);
    m = fmaxf(m, __shfl_xor(m, 1));
    m = fmaxf(m, __shfl_xor(m, 2));
    m = fmaxf(m, __shfl_xor(m, 4));
    m = fmaxf(m, __shfl_xor(m, 8));
    mx[rr] = m;
  }
  #pragma unroll
  for (int nt = 0; nt < 13; ++nt)
    #pragma unroll
    for (int rr = 0; rr < 4; ++rr)
      s[nt][rr] = __expf(s[nt][rr] - mx[rr]);
  #pragma unroll
  for (int rr = 0; rr < 4; ++rr) {
    float d = 0.f;
    #pragma unroll
    for (int nt = 0; nt < 13; ++nt) d += s[nt][rr];
    d += __shfl_xor(d, 1);
    d += __shfl_xor(d, 2);
    d += __shfl_xor(d, 4);
    d += __shfl_xor(d, 8);
    dn[rr] = 1.f / d;
  }
  #pragma unroll
  for (int nt = 0; nt < 13; ++nt)
    #pragma unroll
    for (int rr = 0; rr < 4; ++rr)
      pr[w][(lane >> 4) * 4 + rr][nt * 16 + colbase] = (__bf16)(s[nt][rr] * dn[rr]);
  __syncthreads();

  f32x4 c4[4] = {};
  __builtin_amdgcn_s_setprio(1);
  #pragma unroll
  for (int kc = 0; kc < 7; ++kc) {
    bf16x8 ap = *(const bf16x8*)&pr[w][lane & 15][kc * 32 + (lane >> 4) * 8];
    #pragma unroll
    for (int dt = 0; dt < 4; ++dt) {
      bf16x8 bv = *(const bf16x8*)&vpT[(size_t)((bb * 8 + h) * 64 + dt * 16 + (lane & 15)) * PVK + kc * 32 + (lane >> 4) * 8];
      c4[dt] = MFMA16(ap, bv, c4[dt]);
    }
  }
  __builtin_amdgcn_s_setprio(0);
  #pragma unroll
  for (int dt = 0; dt < 4; ++dt)
    #pragma unroll
    for (int rr = 0; rr < 4; ++rr) {
      const int qrow = row0 + (lane >> 4) * 4 + rr;
      if (qrow < LL)
        ctx[(size_t)(bb * LL + qrow) * DD + h * DHH + dt * 16 + (lane & 15)] = c4[dt][rr];
    }

  {
    const int rr_ = tid >> 5;
    const int c0_ = (tid & 31) * 7;
    const int qrow = row0 + rr_;
    if (qrow < LL) {
      #pragma unroll
      for (int j = 0; j < 7; ++j) {
        const int c = c0_ + j;
        if (c < LL) {
          float sum = 0.f;
          #pragma unroll
          for (int ww = 0; ww < 8; ++ww) sum += (float)pr[ww][rr_][c];
          probs_out[((size_t)bb * LL + qrow) * LL + c] = sum * 0.125f;
        }
      }
    }
  }
}

// ---------------------------------------------------------------------------
// Residual + LayerNorm, in-place on d_out's ctx region. One wave per row.
// ---------------------------------------------------------------------------
__global__ __launch_bounds__(256) void ln_kernel(
    float* __restrict__ ctx, const float* __restrict__ resid,
    const float* __restrict__ gamma, const float* __restrict__ beta)
{
  const int tid = threadIdx.x;
  const int w = tid >> 6, lane = tid & 63;
  const int row = blockIdx.x * 4 + w;
  float* crow = ctx + (size_t)row * DD;
  const float* rrow = resid + (size_t)row * DD;
  const int c = lane * 8;

  float4 a0 = *(const float4*)(crow + c);
  float4 a1 = *(const float4*)(crow + c + 4);
  float4 b0 = *(const float4*)(rrow + c);
  float4 b1 = *(const float4*)(rrow + c + 4);
  float v[8] = {a0.x + b0.x, a0.y + b0.y, a0.z + b0.z, a0.w + b0.w,
                a1.x + b1.x, a1.y + b1.y, a1.z + b1.z, a1.w + b1.w};

  float sum = 0.f;
  #pragma unroll
  for (int j = 0; j < 8; ++j) sum += v[j];
  #pragma unroll
  for (int o = 1; o < 64; o <<= 1) sum += __shfl_xor(sum, o);
  const float mu = sum * (1.f / (float)DD);

  float var = 0.f;
  #pragma unroll
  for (int j = 0; j < 8; ++j) { float d = v[j] - mu; var += d * d; }
  #pragma unroll
  for (int o = 1; o < 64; o <<= 1) var += __shfl_xor(var, o);
  const float rstd = rsqrtf(var * (1.f / (float)DD) + 1e-6f);

  float4 g0 = *(const float4*)(gamma + c);
  float4 g1 = *(const float4*)(gamma + c + 4);
  float4 e0 = *(const float4*)(beta + c);
  float4 e1 = *(const float4*)(beta + c + 4);
  float g[8] = {g0.x, g0.y, g0.z, g0.w, g1.x, g1.y, g1.z, g1.w};
  float e[8] = {e0.x, e0.y, e0.z, e0.w, e1.x, e1.y, e1.z, e1.w};

  float o_[8];
  #pragma unroll
  for (int j = 0; j < 8; ++j) o_[j] = (v[j] - mu) * rstd * g[j] + e[j];
  *(float4*)(crow + c)     = make_float4(o_[0], o_[1], o_[2], o_[3]);
  *(float4*)(crow + c + 4) = make_float4(o_[4], o_[5], o_[6], o_[7]);
}

// ---------------------------------------------------------------------------
extern "C" void kernel_launch(void* const* d_in, const int* in_sizes, int n_in,
                              void* d_out, int out_size, void* d_ws, size_t ws_size,
                              hipStream_t stream)
{
  const float* xq    = (const float*)d_in[0];
  const float* xk    = (const float*)d_in[1];
  const float* xv    = (const float*)d_in[2];
  const float* Wq    = (const float*)d_in[3];
  const float* bq    = (const float*)d_in[4];
  const float* Wk    = (const float*)d_in[5];
  const float* bk    = (const float*)d_in[6];
  const float* Wv    = (const float*)d_in[7];
  const float* bv    = (const float*)d_in[8];
  const float* gamma = (const float*)d_in[9];
  const float* beta  = (const float*)d_in[10];
  const float* ls    = (const float*)d_in[11];

  float* out_ctx    = (float*)d_out;
  float* out_logits = out_ctx + (size_t)BL * DD;
  float* out_probs  = out_logits + BB * BB;

  const size_t xsz = (size_t)BL * DD;     // 3,211,264
  const size_t wsz = (size_t)DD * DD;     // 262,144
  const size_t qsz = (size_t)NPAD * DD;   // 3,276,800 (padded rows for retrieve)
  __bf16* xb = (__bf16*)d_ws;             // 3 * xsz
  __bf16* wb = xb + 3 * xsz;              // 3 * wsz
  __bf16* qp = wb + 3 * wsz;              // qsz
  __bf16* kp = qp + qsz;                  // qsz
  __bf16* vp = kp + qsz;                  // xsz
  // xb region is dead after proj_gemm: reuse for vpT and rmax/cmax
  __bf16* vpT = xb;                       // 16384 * 224 bf16
  unsigned* rmax = (unsigned*)(xb + 3670016);
  unsigned* cmax = rmax + (size_t)BB * BL;

  cvt_kernel<<<dim3(1696, 3), 256, 0, stream>>>(xq, xk, xv, Wq, Wk, Wv, xb, wb);

  proj_gemm_kernel<<<dim3(49, 4, 3), 256, 0, stream>>>(xb, wb, bq, bk, bv, qp, kp, vp);

  transpose_v_kernel<<<dim3(BB * HH, 4), 256, 0, stream>>>(vp, vpT);

  // zero the pad rows (6272..6399) of qp/kp and the max tables
  hipMemsetAsync(qp + (size_t)BL * DD, 0, (size_t)(NPAD - BL) * DD * sizeof(__bf16), stream);
  hipMemsetAsync(kp + (size_t)BL * DD, 0, (size_t)(NPAD - BL) * DD * sizeof(__bf16), stream);
  hipMemsetAsync(rmax, 0, (size_t)2 * BB * BL * sizeof(unsigned), stream);

  retrieve_kernel<<<625, 512, 0, stream>>>(qp, kp, rmax, cmax);
  finish_kernel<<<256, 256, 0, stream>>>(rmax, cmax, ls, out_logits);

  attn_kernel<<<dim3(BB, 13), 512, 0, stream>>>(qp, kp, vpT, out_ctx, out_probs);
  ln_kernel<<<BL / 4, 256, 0, stream>>>(out_ctx, xq, gamma, beta);
}

// Round 6
// 232.250 us; speedup vs baseline: 1.1197x; 1.1197x over previous
//
#include <hip/hip_runtime.h>
#include <hip/hip_bf16.h>

#define BB 32
#define LL 196
#define DD 512
#define HH 8
#define DHH 64
#define BL (BB*LL)   // 6272
#define PVK 224      // padded m-dim for PV (7 * 32)
#define PSTR 236     // pr LDS stride (bf16)
#define CSTR 528     // fused-LN ctx tile stride (f32)

typedef __bf16 bf16x8 __attribute__((ext_vector_type(8)));
typedef float f32x4 __attribute__((ext_vector_type(4)));

#define MFMA16(a,b,c) __builtin_amdgcn_mfma_f32_16x16x32_bf16((a),(b),(c),0,0,0)

#define GLOAD_LDS16(g, l) __builtin_amdgcn_global_load_lds( \
    (const __attribute__((address_space(1))) void*)(g), \
    (__attribute__((address_space(3))) void*)(l), 16, 0, 0)

static __device__ __forceinline__ bf16x8 pack8(float4 v0, float4 v1) {
  bf16x8 o;
  o[0] = (__bf16)v0.x; o[1] = (__bf16)v0.y; o[2] = (__bf16)v0.z; o[3] = (__bf16)v0.w;
  o[4] = (__bf16)v1.x; o[5] = (__bf16)v1.y; o[6] = (__bf16)v1.z; o[7] = (__bf16)v1.w;
  return o;
}

static __device__ __forceinline__ unsigned fkey(float f) {
  unsigned u = __float_as_uint(f);
  return u ^ ((unsigned)((int)u >> 31) | 0x80000000u);
}
static __device__ __forceinline__ float unkey(unsigned k) {
  unsigned u = (k & 0x80000000u) ? (k ^ 0x80000000u) : ~k;
  return __uint_as_float(u);
}

// Stage a 128x64 bf16 tile pair into LDS, linear dest, inverse-swizzled source.
#define STAGE_PAIR(SA, SB, abase, bbase) do { \
  const __bf16* aB_ = (abase); const __bf16* bB_ = (bbase); \
  _Pragma("unroll") \
  for (int c_ = 0; c_ < 4; ++c_) { \
    const int p_ = c_ * 256 + tid; \
    GLOAD_LDS16(aB_ + (size_t)(p_ >> 3) * DD + swoff, &SA[p_ * 8]); \
  } \
  _Pragma("unroll") \
  for (int c_ = 0; c_ < 4; ++c_) { \
    const int p_ = c_ * 256 + tid; \
    GLOAD_LDS16(bB_ + (size_t)(p_ >> 3) * DD + swoff, &SB[p_ * 8]); \
  } \
} while (0)

// 16 MFMA K-step on a staged tile pair, swizzled ds_read addressing.
#define COMPUTE_TILE(SA, SB) do { \
  _Pragma("unroll") \
  for (int kc_ = 0; kc_ < 2; ++kc_) { \
    const int q_ = (((kc_ * 4 + (lane >> 4)) ^ (lane & 7)) << 3); \
    bf16x8 af_[4], bf_[4]; \
    _Pragma("unroll") \
    for (int mt_ = 0; mt_ < 4; ++mt_) \
      af_[mt_] = *(const bf16x8*)&SA[(wr + mt_ * 16 + (lane & 15)) * 64 + q_]; \
    _Pragma("unroll") \
    for (int nt_ = 0; nt_ < 4; ++nt_) \
      bf_[nt_] = *(const bf16x8*)&SB[(wc + nt_ * 16 + (lane & 15)) * 64 + q_]; \
    _Pragma("unroll") \
    for (int mt_ = 0; mt_ < 4; ++mt_) \
      _Pragma("unroll") \
      for (int nt_ = 0; nt_ < 4; ++nt_) \
        acc[mt_][nt_] = MFMA16(af_[mt_], bf_[nt_], acc[mt_][nt_]); \
  } \
} while (0)

// ---------------------------------------------------------------------------
// f32 -> bf16 bulk convert: X (3 x 6272x512) and W (3 x 512x512)
// ---------------------------------------------------------------------------
__global__ __launch_bounds__(256) void cvt_kernel(
    const float* __restrict__ x0, const float* __restrict__ x1, const float* __restrict__ x2,
    const float* __restrict__ w0, const float* __restrict__ w1, const float* __restrict__ w2,
    __bf16* __restrict__ xb, __bf16* __restrict__ wb)
{
  const int z = blockIdx.y;
  const float* src; __bf16* dst; size_t i;
  if (blockIdx.x < 1568) {
    src = (z == 0) ? x0 : (z == 1) ? x1 : x2;
    dst = xb + (size_t)z * 3211264;
    i = (size_t)blockIdx.x * 256 + threadIdx.x;
  } else {
    src = (z == 0) ? w0 : (z == 1) ? w1 : w2;
    dst = wb + (size_t)z * 262144;
    i = (size_t)(blockIdx.x - 1568) * 256 + threadIdx.x;
  }
  const float4* s = (const float4*)(src + i * 8);
  float4 a = s[0], b = s[1];
  *(bf16x8*)(dst + i * 8) = pack8(a, b);
}

// ---------------------------------------------------------------------------
// Projection NT GEMM (bf16 in/out), 128x128 tile, single-buffer m97 structure
// grid (49, 4, 3), block 256
// ---------------------------------------------------------------------------
__global__ __launch_bounds__(256) void proj_gemm_kernel(
    const __bf16* __restrict__ xb, const __bf16* __restrict__ wb,
    const float* __restrict__ bq, const float* __restrict__ bk, const float* __restrict__ bv,
    __bf16* __restrict__ qp, __bf16* __restrict__ kp, __bf16* __restrict__ vp)
{
  __shared__ __bf16 sA[128 * 64];
  __shared__ __bf16 sB[128 * 64];

  const int z = blockIdx.z;
  const __bf16* A = xb + (size_t)z * 3211264;
  const __bf16* B = wb + (size_t)z * 262144;
  const float* bias = (z == 0) ? bq : (z == 1) ? bk : bv;
  __bf16* out = (z == 0) ? qp : (z == 1) ? kp : vp;

  const int tid = threadIdx.x;
  const int w = tid >> 6, lane = tid & 63;
  const int wr = (w >> 1) * 64, wc = (w & 1) * 64;
  const int bm = blockIdx.x * 128, bn = blockIdx.y * 128;
  const int swoff = ((tid & 7) ^ ((tid >> 3) & 7)) << 3;

  const __bf16* aP = A + (size_t)bm * DD;
  const __bf16* bP = B + (size_t)bn * DD;

  f32x4 acc[4][4] = {};

  #pragma unroll
  for (int kt = 0; kt < 8; ++kt) {
    STAGE_PAIR(sA, sB, aP + kt * 64, bP + kt * 64);
    __syncthreads();
    COMPUTE_TILE(sA, sB);
    __syncthreads();
  }

  #pragma unroll
  for (int mt = 0; mt < 4; ++mt)
    #pragma unroll
    for (int nt = 0; nt < 4; ++nt)
      #pragma unroll
      for (int rr = 0; rr < 4; ++rr) {
        const int row = bm + wr + mt * 16 + (lane >> 4) * 4 + rr;
        const int col = bn + wc + nt * 16 + (lane & 15);
        out[(size_t)row * DD + col] = (__bf16)(acc[mt][nt][rr] + bias[col]);
      }
}

// ---------------------------------------------------------------------------
// V transpose: vp[(bb*196+m)][h*64+d] -> vpT[(bb*8+h)*64+d][m] (m padded to 224)
// ---------------------------------------------------------------------------
__global__ __launch_bounds__(256) void transpose_v_kernel(
    const __bf16* __restrict__ vp, __bf16* __restrict__ vpT)
{
  __shared__ __bf16 sT[64][72];
  const int bbh = blockIdx.x;
  const int mt = blockIdx.y;
  const int bb = bbh >> 3, h = bbh & 7;
  const int tid = threadIdx.x;
  {
    const int r = tid >> 2, c0 = (tid & 3) * 16;
    const int m = mt * 64 + r;
    bf16x8 z = {};
    bf16x8 v0 = z, v1 = z;
    if (m < LL) {
      const bf16x8* src = (const bf16x8*)&vp[(size_t)(bb * LL + m) * DD + h * DHH + c0];
      v0 = src[0]; v1 = src[1];
    }
    *(bf16x8*)&sT[r][c0]     = v0;
    *(bf16x8*)&sT[r][c0 + 8] = v1;
  }
  __syncthreads();
  {
    const int d = tid >> 2, mc0 = (tid & 3) * 16;
    if (mt * 64 + mc0 < PVK) {
      bf16x8 o0, o1;
      #pragma unroll
      for (int j = 0; j < 8; ++j) { o0[j] = sT[mc0 + j][d]; o1[j] = sT[mc0 + 8 + j][d]; }
      __bf16* dst = vpT + (size_t)(bbh * 64 + d) * PVK + mt * 64 + mc0;
      *(bf16x8*)dst = o0;
      *(bf16x8*)(dst + 8) = o1;
    }
  }
}

// ---------------------------------------------------------------------------
// Retrieve: flat 6272x6272x512 NT GEMM, single-buffer m97 structure + swizzle
// + fused segment-max epilogue (atomicMax on keyed u32 tables).
// grid 2401, block 256  (round-4 verified: 73 us, 0 bank conflicts)
// ---------------------------------------------------------------------------
__global__ __launch_bounds__(256) void retrieve_kernel(
    const __bf16* __restrict__ qp, const __bf16* __restrict__ kp,
    unsigned* __restrict__ rmax, unsigned* __restrict__ cmax)
{
  __shared__ __bf16 sA[128 * 64];
  __shared__ __bf16 sB[128 * 64];

  // bijective XCD chunking (2401 = 8*300 + 1) then 7x7 supertile decode
  const int orig = blockIdx.x;
  const int xcd = orig & 7, idx = orig >> 3;
  const int wg = (xcd == 0) ? idx : (301 + (xcd - 1) * 300 + idx);
  const int st = wg / 49, wi = wg % 49;
  const int brow = ((st / 7) * 7 + wi / 7) * 128;
  const int bcol = ((st % 7) * 7 + wi % 7) * 128;

  const int tid = threadIdx.x;
  const int w = tid >> 6, lane = tid & 63;
  const int wr = (w >> 1) * 64, wc = (w & 1) * 64;
  const int swoff = ((tid & 7) ^ ((tid >> 3) & 7)) << 3;

  const __bf16* aP = qp + (size_t)brow * DD;
  const __bf16* bP = kp + (size_t)bcol * DD;

  f32x4 acc[4][4] = {};

  #pragma unroll
  for (int kt = 0; kt < 8; ++kt) {
    STAGE_PAIR(sA, sB, aP + kt * 64, bP + kt * 64);
    __syncthreads();
    COMPUTE_TILE(sA, sB);
    __syncthreads();
  }

  const int wcol0 = bcol + wc;
  const int wrow0 = brow + wr;
  // Row-max per 196-col segment (t2v): rmax[b][grow]
  {
    const int b0 = wcol0 / LL, b1 = (wcol0 + 63) / LL;
    for (int b = b0; b <= b1; ++b) {
      const int lo = b * LL, hi = lo + LL;
      #pragma unroll
      for (int mt = 0; mt < 4; ++mt)
        #pragma unroll
        for (int rr = 0; rr < 4; ++rr) {
          float m = -3e38f;
          #pragma unroll
          for (int nt = 0; nt < 4; ++nt) {
            const int col = wcol0 + nt * 16 + (lane & 15);
            if (col >= lo && col < hi) m = fmaxf(m, acc[mt][nt][rr]);
          }
          m = fmaxf(m, __shfl_xor(m, 1));
          m = fmaxf(m, __shfl_xor(m, 2));
          m = fmaxf(m, __shfl_xor(m, 4));
          m = fmaxf(m, __shfl_xor(m, 8));
          if ((lane & 15) == 0) {
            const int grow = wrow0 + mt * 16 + (lane >> 4) * 4 + rr;
            atomicMax(&rmax[(size_t)b * BL + grow], fkey(m));
          }
        }
    }
  }
  // Col-max per 196-row segment (v2t): cmax[a][col]
  {
    const int a0 = wrow0 / LL, a1 = (wrow0 + 63) / LL;
    for (int a = a0; a <= a1; ++a) {
      const int lo = a * LL, hi = lo + LL;
      #pragma unroll
      for (int nt = 0; nt < 4; ++nt) {
        float cm = -3e38f;
        #pragma unroll
        for (int mt = 0; mt < 4; ++mt)
          #pragma unroll
          for (int rr = 0; rr < 4; ++rr) {
            const int grow = wrow0 + mt * 16 + (lane >> 4) * 4 + rr;
            if (grow >= lo && grow < hi) cm = fmaxf(cm, acc[mt][nt][rr]);
          }
        cm = fmaxf(cm, __shfl_xor(cm, 16));
        cm = fmaxf(cm, __shfl_xor(cm, 32));
        if (lane < 16) {
          const int col = wcol0 + nt * 16 + lane;
          atomicMax(&cmax[(size_t)a * BL + col], fkey(cm));
        }
      }
    }
  }
}

// ---------------------------------------------------------------------------
// Fold rmax/cmax into logits. grid 256, block 256 (one wave per (a,b))
// ---------------------------------------------------------------------------
__global__ __launch_bounds__(256) void finish_kernel(
    const unsigned* __restrict__ rmax, const unsigned* __restrict__ cmax,
    const float* __restrict__ ls, float* __restrict__ out_logits)
{
  const int tid = threadIdx.x;
  const int w = tid >> 6, lane = tid & 63;
  const int pair = blockIdx.x * 4 + w;
  const int a = pair >> 5, b = pair & 31;
  float s = 0.f;
  #pragma unroll
  for (int k = 0; k < 4; ++k) {
    const int l = lane + k * 64;
    if (l < LL) {
      s += unkey(rmax[(size_t)b * BL + a * LL + l]);
      s += unkey(cmax[(size_t)a * BL + b * LL + l]);
    }
  }
  #pragma unroll
  for (int o = 1; o < 64; o <<= 1) s += __shfl_xor(s, o);
  if (lane == 0)
    out_logits[a * BB + b] = expf(ls[0]) * s * (0.5f / (float)LL);
}

// ---------------------------------------------------------------------------
// Self-attention + residual + LayerNorm fused.
// block = (bb, strip of 16 q-rows); 8 waves = 1 head each.
// After PV + probs-mean, ctx tile goes to LDS (union over pr) and the block
// LayerNorms its 16 rows directly to the output. grid (32, 13), block 512
// ---------------------------------------------------------------------------
__global__ __launch_bounds__(512) void attn_kernel(
    const __bf16* __restrict__ qp, const __bf16* __restrict__ kp,
    const __bf16* __restrict__ vpT, const float* __restrict__ resid,
    const float* __restrict__ gamma, const float* __restrict__ beta,
    float* __restrict__ out_ctx, float* __restrict__ probs_out)
{
  __shared__ __align__(16) char smem[8 * 16 * PSTR * 2];   // 60,416 B
  auto pr    = (__bf16(*)[16][PSTR])smem;                  // [8][16][PSTR]
  auto ctile = (float(*)[CSTR])smem;                       // [16][CSTR] (reuse)

  const int bb = blockIdx.x;
  const int strip = blockIdx.y;
  const int tid = threadIdx.x;
  const int w = tid >> 6, lane = tid & 63;   // w == head
  const int h = w;
  const int row0 = strip * 16;

  for (int i = lane; i < 256; i += 64)
    pr[w][i >> 4][208 + (i & 15)] = (__bf16)0.f;

  const int arow = row0 + (lane & 15);
  const bool aval = arow < LL;

  bf16x8 aq[2];
  #pragma unroll
  for (int kc = 0; kc < 2; ++kc) {
    bf16x8 z = {};
    aq[kc] = aval
      ? *(const bf16x8*)&qp[(size_t)(bb * LL + arow) * DD + h * DHH + kc * 32 + (lane >> 4) * 8]
      : z;
  }
  f32x4 s[13] = {};
  __builtin_amdgcn_s_setprio(1);
  #pragma unroll
  for (int nt = 0; nt < 13; ++nt) {
    const int brow = nt * 16 + (lane & 15);
    #pragma unroll
    for (int kc = 0; kc < 2; ++kc) {
      bf16x8 bk = {};
      if (brow < LL)
        bk = *(const bf16x8*)&kp[(size_t)(bb * LL + brow) * DD + h * DHH + kc * 32 + (lane >> 4) * 8];
      s[nt] = MFMA16(aq[kc], bk, s[nt]);
    }
  }
  __builtin_amdgcn_s_setprio(0);

  const int colbase = lane & 15;
  #pragma unroll
  for (int nt = 0; nt < 13; ++nt) {
    const bool cv = (nt * 16 + colbase) < LL;
    #pragma unroll
    for (int rr = 0; rr < 4; ++rr)
      s[nt][rr] = cv ? s[nt][rr] * 0.125f : -1e30f;
  }
  float mx[4], dn[4];
  #pragma unroll
  for (int rr = 0; rr < 4; ++rr) {
    float m = s[0][rr];
    #pragma unroll
    for (int nt = 1; nt < 13; ++nt) m = fmaxf(m, s[nt][rr]);
    m = fmaxf(m, __shfl_xor(m, 1));
    m = fmaxf(m, __shfl_xor(m, 2));
    m = fmaxf(m, __shfl_xor(m, 4));
    m = fmaxf(m, __shfl_xor(m, 8));
    mx[rr] = m;
  }
  #pragma unroll
  for (int nt = 0; nt < 13; ++nt)
    #pragma unroll
    for (int rr = 0; rr < 4; ++rr)
      s[nt][rr] = __expf(s[nt][rr] - mx[rr]);
  #pragma unroll
  for (int rr = 0; rr < 4; ++rr) {
    float d = 0.f;
    #pragma unroll
    for (int nt = 0; nt < 13; ++nt) d += s[nt][rr];
    d += __shfl_xor(d, 1);
    d += __shfl_xor(d, 2);
    d += __shfl_xor(d, 4);
    d += __shfl_xor(d, 8);
    dn[rr] = 1.f / d;
  }
  #pragma unroll
  for (int nt = 0; nt < 13; ++nt)
    #pragma unroll
    for (int rr = 0; rr < 4; ++rr)
      pr[w][(lane >> 4) * 4 + rr][nt * 16 + colbase] = (__bf16)(s[nt][rr] * dn[rr]);
  __syncthreads();

  // PV: A = pr[w], B = vpT (global, L2-hot)
  f32x4 c4[4] = {};
  __builtin_amdgcn_s_setprio(1);
  #pragma unroll
  for (int kc = 0; kc < 7; ++kc) {
    bf16x8 ap = *(const bf16x8*)&pr[w][lane & 15][kc * 32 + (lane >> 4) * 8];
    #pragma unroll
    for (int dt = 0; dt < 4; ++dt) {
      bf16x8 bv = *(const bf16x8*)&vpT[(size_t)((bb * 8 + h) * 64 + dt * 16 + (lane & 15)) * PVK + kc * 32 + (lane >> 4) * 8];
      c4[dt] = MFMA16(ap, bv, c4[dt]);
    }
  }
  __builtin_amdgcn_s_setprio(0);

  // probs-mean: coalesced — thread covers col (tid&31) + j*32 of row tid>>5
  {
    const int rr_ = tid >> 5;
    const int qrow = row0 + rr_;
    if (qrow < LL) {
      #pragma unroll
      for (int j = 0; j < 7; ++j) {
        const int c = (tid & 31) + j * 32;
        if (c < LL) {
          float sum = 0.f;
          #pragma unroll
          for (int ww = 0; ww < 8; ++ww) sum += (float)pr[ww][rr_][c];
          probs_out[((size_t)bb * LL + qrow) * LL + c] = sum * 0.125f;
        }
      }
    }
  }
  __syncthreads();   // all pr reads done; smem can be reused as ctile

  // scatter c4 into the f32 ctx tile
  #pragma unroll
  for (int dt = 0; dt < 4; ++dt)
    #pragma unroll
    for (int rr = 0; rr < 4; ++rr)
      ctile[(lane >> 4) * 4 + rr][h * DHH + dt * 16 + (lane & 15)] = c4[dt][rr];
  __syncthreads();

  // fused residual + LayerNorm: wave w handles rows 2w, 2w+1
  #pragma unroll
  for (int rsel = 0; rsel < 2; ++rsel) {
    const int r = w * 2 + rsel;
    const int qrow = row0 + r;
    if (qrow >= LL) continue;
    const int c = lane * 8;
    const float* rrow = resid + (size_t)(bb * LL + qrow) * DD;
    float4 a0 = *(const float4*)&ctile[r][c];
    float4 a1 = *(const float4*)&ctile[r][c + 4];
    float4 b0 = *(const float4*)(rrow + c);
    float4 b1 = *(const float4*)(rrow + c + 4);
    float v[8] = {a0.x + b0.x, a0.y + b0.y, a0.z + b0.z, a0.w + b0.w,
                  a1.x + b1.x, a1.y + b1.y, a1.z + b1.z, a1.w + b1.w};
    float sum = 0.f;
    #pragma unroll
    for (int j = 0; j < 8; ++j) sum += v[j];
    #pragma unroll
    for (int o = 1; o < 64; o <<= 1) sum += __shfl_xor(sum, o);
    const float mu = sum * (1.f / (float)DD);
    float var = 0.f;
    #pragma unroll
    for (int j = 0; j < 8; ++j) { float d = v[j] - mu; var += d * d; }
    #pragma unroll
    for (int o = 1; o < 64; o <<= 1) var += __shfl_xor(var, o);
    const float rstd = rsqrtf(var * (1.f / (float)DD) + 1e-6f);
    float4 g0 = *(const float4*)(gamma + c);
    float4 g1 = *(const float4*)(gamma + c + 4);
    float4 e0 = *(const float4*)(beta + c);
    float4 e1 = *(const float4*)(beta + c + 4);
    float g[8] = {g0.x, g0.y, g0.z, g0.w, g1.x, g1.y, g1.z, g1.w};
    float e[8] = {e0.x, e0.y, e0.z, e0.w, e1.x, e1.y, e1.z, e1.w};
    float o_[8];
    #pragma unroll
    for (int j = 0; j < 8; ++j) o_[j] = (v[j] - mu) * rstd * g[j] + e[j];
    float* orow = out_ctx + (size_t)(bb * LL + qrow) * DD;
    *(float4*)(orow + c)     = make_float4(o_[0], o_[1], o_[2], o_[3]);
    *(float4*)(orow + c + 4) = make_float4(o_[4], o_[5], o_[6], o_[7]);
  }
}

// ---------------------------------------------------------------------------
extern "C" void kernel_launch(void* const* d_in, const int* in_sizes, int n_in,
                              void* d_out, int out_size, void* d_ws, size_t ws_size,
                              hipStream_t stream)
{
  const float* xq    = (const float*)d_in[0];
  const float* xk    = (const float*)d_in[1];
  const float* xv    = (const float*)d_in[2];
  const float* Wq    = (const float*)d_in[3];
  const float* bq    = (const float*)d_in[4];
  const float* Wk    = (const float*)d_in[5];
  const float* bk    = (const float*)d_in[6];
  const float* Wv    = (const float*)d_in[7];
  const float* bv    = (const float*)d_in[8];
  const float* gamma = (const float*)d_in[9];
  const float* beta  = (const float*)d_in[10];
  const float* ls    = (const float*)d_in[11];

  float* out_ctx    = (float*)d_out;
  float* out_logits = out_ctx + (size_t)BL * DD;
  float* out_probs  = out_logits + BB * BB;

  const size_t xsz = (size_t)BL * DD;   // 3,211,264
  const size_t wsz = (size_t)DD * DD;   // 262,144
  __bf16* xb = (__bf16*)d_ws;           // 3 * xsz
  __bf16* wb = xb + 3 * xsz;            // 3 * wsz
  __bf16* qp = wb + 3 * wsz;
  __bf16* kp = qp + xsz;
  __bf16* vp = kp + xsz;
  // xb region is dead after proj_gemm: reuse it for vpT and rmax/cmax
  __bf16* vpT = xb;                                  // 16384 * 224 bf16
  unsigned* rmax = (unsigned*)(xb + 3670016);        // 6272*32 u32
  unsigned* cmax = rmax + (size_t)BB * BL;

  cvt_kernel<<<dim3(1696, 3), 256, 0, stream>>>(xq, xk, xv, Wq, Wk, Wv, xb, wb);

  proj_gemm_kernel<<<dim3(49, 4, 3), 256, 0, stream>>>(xb, wb, bq, bk, bv, qp, kp, vp);

  transpose_v_kernel<<<dim3(BB * HH, 4), 256, 0, stream>>>(vp, vpT);

  hipMemsetAsync(rmax, 0, (size_t)2 * BB * BL * sizeof(unsigned), stream);

  retrieve_kernel<<<2401, 256, 0, stream>>>(qp, kp, rmax, cmax);
  finish_kernel<<<256, 256, 0, stream>>>(rmax, cmax, ls, out_logits);

  attn_kernel<<<dim3(BB, 13), 512, 0, stream>>>(qp, kp, vpT, xq, gamma, beta,
                                                out_ctx, out_probs);
}

// Round 9
// 231.142 us; speedup vs baseline: 1.1250x; 1.0048x over previous
//
#include <hip/hip_runtime.h>
#include <hip/hip_bf16.h>

#define BB 32
#define LL 196
#define DD 512
#define HH 8
#define DHH 64
#define BL (BB*LL)   // 6272
#define PVK 224      // padded m-dim for PV (7 * 32)
#define PSTR 236     // pr LDS stride (bf16)
#define CSTR 528     // fused-LN ctx tile stride (f32)

typedef __bf16 bf16x8 __attribute__((ext_vector_type(8)));
typedef float f32x4 __attribute__((ext_vector_type(4)));

#define MFMA16(a,b,c) __builtin_amdgcn_mfma_f32_16x16x32_bf16((a),(b),(c),0,0,0)

#define GLOAD_LDS16(g, l) __builtin_amdgcn_global_load_lds( \
    (const __attribute__((address_space(1))) void*)(g), \
    (__attribute__((address_space(3))) void*)(l), 16, 0, 0)

static __device__ __forceinline__ bf16x8 pack8(float4 v0, float4 v1) {
  bf16x8 o;
  o[0] = (__bf16)v0.x; o[1] = (__bf16)v0.y; o[2] = (__bf16)v0.z; o[3] = (__bf16)v0.w;
  o[4] = (__bf16)v1.x; o[5] = (__bf16)v1.y; o[6] = (__bf16)v1.z; o[7] = (__bf16)v1.w;
  return o;
}

static __device__ __forceinline__ unsigned fkey(float f) {
  unsigned u = __float_as_uint(f);
  return u ^ ((unsigned)((int)u >> 31) | 0x80000000u);
}
static __device__ __forceinline__ float unkey(unsigned k) {
  unsigned u = (k & 0x80000000u) ? (k ^ 0x80000000u) : ~k;
  return __uint_as_float(u);
}

// Stage a 128x64 bf16 tile pair into LDS, linear dest, inverse-swizzled source.
#define STAGE_PAIR(SA, SB, abase, bbase) do { \
  const __bf16* aB_ = (abase); const __bf16* bB_ = (bbase); \
  _Pragma("unroll") \
  for (int c_ = 0; c_ < 4; ++c_) { \
    const int p_ = c_ * 256 + tid; \
    GLOAD_LDS16(aB_ + (size_t)(p_ >> 3) * DD + swoff, &SA[p_ * 8]); \
  } \
  _Pragma("unroll") \
  for (int c_ = 0; c_ < 4; ++c_) { \
    const int p_ = c_ * 256 + tid; \
    GLOAD_LDS16(bB_ + (size_t)(p_ >> 3) * DD + swoff, &SB[p_ * 8]); \
  } \
} while (0)

// 16 MFMA K-step on a staged tile pair, swizzled ds_read addressing.
#define COMPUTE_TILE(SA, SB) do { \
  _Pragma("unroll") \
  for (int kc_ = 0; kc_ < 2; ++kc_) { \
    const int q_ = (((kc_ * 4 + (lane >> 4)) ^ (lane & 7)) << 3); \
    bf16x8 af_[4], bf_[4]; \
    _Pragma("unroll") \
    for (int mt_ = 0; mt_ < 4; ++mt_) \
      af_[mt_] = *(const bf16x8*)&SA[(wr + mt_ * 16 + (lane & 15)) * 64 + q_]; \
    _Pragma("unroll") \
    for (int nt_ = 0; nt_ < 4; ++nt_) \
      bf_[nt_] = *(const bf16x8*)&SB[(wc + nt_ * 16 + (lane & 15)) * 64 + q_]; \
    _Pragma("unroll") \
    for (int mt_ = 0; mt_ < 4; ++mt_) \
      _Pragma("unroll") \
      for (int nt_ = 0; nt_ < 4; ++nt_) \
        acc[mt_][nt_] = MFMA16(af_[mt_], bf_[nt_], acc[mt_][nt_]); \
  } \
} while (0)

// ---------------------------------------------------------------------------
// f32 -> bf16 bulk convert: X (3 x 6272x512) and W (3 x 512x512)
// ---------------------------------------------------------------------------
__global__ __launch_bounds__(256) void cvt_kernel(
    const float* __restrict__ x0, const float* __restrict__ x1, const float* __restrict__ x2,
    const float* __restrict__ w0, const float* __restrict__ w1, const float* __restrict__ w2,
    __bf16* __restrict__ xb, __bf16* __restrict__ wb)
{
  const int z = blockIdx.y;
  const float* src; __bf16* dst; size_t i;
  if (blockIdx.x < 1568) {
    src = (z == 0) ? x0 : (z == 1) ? x1 : x2;
    dst = xb + (size_t)z * 3211264;
    i = (size_t)blockIdx.x * 256 + threadIdx.x;
  } else {
    src = (z == 0) ? w0 : (z == 1) ? w1 : w2;
    dst = wb + (size_t)z * 262144;
    i = (size_t)(blockIdx.x - 1568) * 256 + threadIdx.x;
  }
  const float4* s = (const float4*)(src + i * 8);
  float4 a = s[0], b = s[1];
  *(bf16x8*)(dst + i * 8) = pack8(a, b);
}

// ---------------------------------------------------------------------------
// Projection NT GEMM (bf16 in/out), 128x128 tile, single-buffer m97 structure
// grid (49, 4, 3), block 256
// ---------------------------------------------------------------------------
__global__ __launch_bounds__(256) void proj_gemm_kernel(
    const __bf16* __restrict__ xb, const __bf16* __restrict__ wb,
    const float* __restrict__ bq, const float* __restrict__ bk, const float* __restrict__ bv,
    __bf16* __restrict__ qp, __bf16* __restrict__ kp, __bf16* __restrict__ vp)
{
  __shared__ __bf16 sA[128 * 64];
  __shared__ __bf16 sB[128 * 64];

  const int z = blockIdx.z;
  const __bf16* A = xb + (size_t)z * 3211264;
  const __bf16* B = wb + (size_t)z * 262144;
  const float* bias = (z == 0) ? bq : (z == 1) ? bk : bv;
  __bf16* out = (z == 0) ? qp : (z == 1) ? kp : vp;

  const int tid = threadIdx.x;
  const int w = tid >> 6, lane = tid & 63;
  const int wr = (w >> 1) * 64, wc = (w & 1) * 64;
  const int bm = blockIdx.x * 128, bn = blockIdx.y * 128;
  const int swoff = ((tid & 7) ^ ((tid >> 3) & 7)) << 3;

  const __bf16* aP = A + (size_t)bm * DD;
  const __bf16* bP = B + (size_t)bn * DD;

  f32x4 acc[4][4] = {};

  #pragma unroll
  for (int kt = 0; kt < 8; ++kt) {
    STAGE_PAIR(sA, sB, aP + kt * 64, bP + kt * 64);
    __syncthreads();
    COMPUTE_TILE(sA, sB);
    __syncthreads();
  }

  #pragma unroll
  for (int mt = 0; mt < 4; ++mt)
    #pragma unroll
    for (int nt = 0; nt < 4; ++nt)
      #pragma unroll
      for (int rr = 0; rr < 4; ++rr) {
        const int row = bm + wr + mt * 16 + (lane >> 4) * 4 + rr;
        const int col = bn + wc + nt * 16 + (lane & 15);
        out[(size_t)row * DD + col] = (__bf16)(acc[mt][nt][rr] + bias[col]);
      }
}

// ---------------------------------------------------------------------------
// V transpose: vp[(bb*196+m)][h*64+d] -> vpT[(bb*8+h)*64+d][m] (m padded to 224)
// ---------------------------------------------------------------------------
__global__ __launch_bounds__(256) void transpose_v_kernel(
    const __bf16* __restrict__ vp, __bf16* __restrict__ vpT)
{
  __shared__ __bf16 sT[64][72];
  const int bbh = blockIdx.x;
  const int mt = blockIdx.y;
  const int bb = bbh >> 3, h = bbh & 7;
  const int tid = threadIdx.x;
  {
    const int r = tid >> 2, c0 = (tid & 3) * 16;
    const int m = mt * 64 + r;
    bf16x8 z = {};
    bf16x8 v0 = z, v1 = z;
    if (m < LL) {
      const bf16x8* src = (const bf16x8*)&vp[(size_t)(bb * LL + m) * DD + h * DHH + c0];
      v0 = src[0]; v1 = src[1];
    }
    *(bf16x8*)&sT[r][c0]     = v0;
    *(bf16x8*)&sT[r][c0 + 8] = v1;
  }
  __syncthreads();
  {
    const int d = tid >> 2, mc0 = (tid & 3) * 16;
    if (mt * 64 + mc0 < PVK) {
      bf16x8 o0, o1;
      #pragma unroll
      for (int j = 0; j < 8; ++j) { o0[j] = sT[mc0 + j][d]; o1[j] = sT[mc0 + 8 + j][d]; }
      __bf16* dst = vpT + (size_t)(bbh * 64 + d) * PVK + mt * 64 + mc0;
      *(bf16x8*)dst = o0;
      *(bf16x8*)(dst + 8) = o1;
    }
  }
}

// ---------------------------------------------------------------------------
// Retrieve: flat 6272x6272x512 NT GEMM, single-buffer m97 structure + swizzle
// + fused segment-max epilogue (atomicMax on keyed u32 tables).
// grid 2401, block 256  (verified: ~73 us, 0 bank conflicts)
// ---------------------------------------------------------------------------
__global__ __launch_bounds__(256) void retrieve_kernel(
    const __bf16* __restrict__ qp, const __bf16* __restrict__ kp,
    unsigned* __restrict__ rmax, unsigned* __restrict__ cmax)
{
  __shared__ __bf16 sA[128 * 64];
  __shared__ __bf16 sB[128 * 64];

  // bijective XCD chunking (2401 = 8*300 + 1) then 7x7 supertile decode
  const int orig = blockIdx.x;
  const int xcd = orig & 7, idx = orig >> 3;
  const int wg = (xcd == 0) ? idx : (301 + (xcd - 1) * 300 + idx);
  const int st = wg / 49, wi = wg % 49;
  const int brow = ((st / 7) * 7 + wi / 7) * 128;
  const int bcol = ((st % 7) * 7 + wi % 7) * 128;

  const int tid = threadIdx.x;
  const int w = tid >> 6, lane = tid & 63;
  const int wr = (w >> 1) * 64, wc = (w & 1) * 64;
  const int swoff = ((tid & 7) ^ ((tid >> 3) & 7)) << 3;

  const __bf16* aP = qp + (size_t)brow * DD;
  const __bf16* bP = kp + (size_t)bcol * DD;

  f32x4 acc[4][4] = {};

  #pragma unroll
  for (int kt = 0; kt < 8; ++kt) {
    STAGE_PAIR(sA, sB, aP + kt * 64, bP + kt * 64);
    __syncthreads();
    COMPUTE_TILE(sA, sB);
    __syncthreads();
  }

  const int wcol0 = bcol + wc;
  const int wrow0 = brow + wr;
  // Row-max per 196-col segment (t2v): rmax[b][grow]
  {
    const int b0 = wcol0 / LL, b1 = (wcol0 + 63) / LL;
    for (int b = b0; b <= b1; ++b) {
      const int lo = b * LL, hi = lo + LL;
      #pragma unroll
      for (int mt = 0; mt < 4; ++mt)
        #pragma unroll
        for (int rr = 0; rr < 4; ++rr) {
          float m = -3e38f;
          #pragma unroll
          for (int nt = 0; nt < 4; ++nt) {
            const int col = wcol0 + nt * 16 + (lane & 15);
            if (col >= lo && col < hi) m = fmaxf(m, acc[mt][nt][rr]);
          }
          m = fmaxf(m, __shfl_xor(m, 1));
          m = fmaxf(m, __shfl_xor(m, 2));
          m = fmaxf(m, __shfl_xor(m, 4));
          m = fmaxf(m, __shfl_xor(m, 8));
          if ((lane & 15) == 0) {
            const int grow = wrow0 + mt * 16 + (lane >> 4) * 4 + rr;
            atomicMax(&rmax[(size_t)b * BL + grow], fkey(m));
          }
        }
    }
  }
  // Col-max per 196-row segment (v2t): cmax[a][col]
  {
    const int a0 = wrow0 / LL, a1 = (wrow0 + 63) / LL;
    for (int a = a0; a <= a1; ++a) {
      const int lo = a * LL, hi = lo + LL;
      #pragma unroll
      for (int nt = 0; nt < 4; ++nt) {
        float cm = -3e38f;
        #pragma unroll
        for (int mt = 0; mt < 4; ++mt)
          #pragma unroll
          for (int rr = 0; rr < 4; ++rr) {
            const int grow = wrow0 + mt * 16 + (lane >> 4) * 4 + rr;
            if (grow >= lo && grow < hi) cm = fmaxf(cm, acc[mt][nt][rr]);
          }
        cm = fmaxf(cm, __shfl_xor(cm, 16));
        cm = fmaxf(cm, __shfl_xor(cm, 32));
        if (lane < 16) {
          const int col = wcol0 + nt * 16 + lane;
          atomicMax(&cmax[(size_t)a * BL + col], fkey(cm));
        }
      }
    }
  }
}

// ---------------------------------------------------------------------------
// Self-attention + residual + LayerNorm + logits-finish fused.
// block = (bb, strip of 16 q-rows); 8 waves = 1 head each.
// V fragments prefetched into registers at entry (hide L2 latency under
// QK^T+softmax). Blocks with strip<8 also fold rmax/cmax into out_logits.
// grid (32, 13), block 512
// ---------------------------------------------------------------------------
__global__ __launch_bounds__(512) void attn_kernel(
    const __bf16* __restrict__ qp, const __bf16* __restrict__ kp,
    const __bf16* __restrict__ vpT, const float* __restrict__ resid,
    const float* __restrict__ gamma, const float* __restrict__ beta,
    const unsigned* __restrict__ rmax, const unsigned* __restrict__ cmax,
    const float* __restrict__ ls,
    float* __restrict__ out_ctx, float* __restrict__ probs_out,
    float* __restrict__ out_logits)
{
  __shared__ __align__(16) char smem[8 * 16 * PSTR * 2];   // 60,416 B
  auto pr    = (__bf16(*)[16][PSTR])smem;                  // [8][16][PSTR]
  auto ctile = (float(*)[CSTR])smem;                       // [16][CSTR] (reuse)

  const int bb = blockIdx.x;
  const int strip = blockIdx.y;
  const int tid = threadIdx.x;
  const int w = tid >> 6, lane = tid & 63;   // w == head
  const int h = w;
  const int row0 = strip * 16;

  // --- prefetch ALL V fragments (independent of everything below) ---
  bf16x8 bvf[4][7];
  #pragma unroll
  for (int dt = 0; dt < 4; ++dt)
    #pragma unroll
    for (int kc = 0; kc < 7; ++kc)
      bvf[dt][kc] = *(const bf16x8*)&vpT[(size_t)((bb * 8 + h) * 64 + dt * 16 + (lane & 15)) * PVK
                                          + kc * 32 + (lane >> 4) * 8];

  for (int i = lane; i < 256; i += 64)
    pr[w][i >> 4][208 + (i & 15)] = (__bf16)0.f;

  const int arow = row0 + (lane & 15);
  const bool aval = arow < LL;

  bf16x8 aq[2];
  #pragma unroll
  for (int kc = 0; kc < 2; ++kc) {
    bf16x8 z = {};
    aq[kc] = aval
      ? *(const bf16x8*)&qp[(size_t)(bb * LL + arow) * DD + h * DHH + kc * 32 + (lane >> 4) * 8]
      : z;
  }
  f32x4 s[13] = {};
  __builtin_amdgcn_s_setprio(1);
  #pragma unroll
  for (int nt = 0; nt < 13; ++nt) {
    const int brow = nt * 16 + (lane & 15);
    #pragma unroll
    for (int kc = 0; kc < 2; ++kc) {
      bf16x8 bk = {};
      if (brow < LL)
        bk = *(const bf16x8*)&kp[(size_t)(bb * LL + brow) * DD + h * DHH + kc * 32 + (lane >> 4) * 8];
      s[nt] = MFMA16(aq[kc], bk, s[nt]);
    }
  }
  __builtin_amdgcn_s_setprio(0);

  const int colbase = lane & 15;
  #pragma unroll
  for (int nt = 0; nt < 13; ++nt) {
    const bool cv = (nt * 16 + colbase) < LL;
    #pragma unroll
    for (int rr = 0; rr < 4; ++rr)
      s[nt][rr] = cv ? s[nt][rr] * 0.125f : -1e30f;
  }
  float mx[4], dn[4];
  #pragma unroll
  for (int rr = 0; rr < 4; ++rr) {
    float m = s[0][rr];
    #pragma unroll
    for (int nt = 1; nt < 13; ++nt) m = fmaxf(m, s[nt][rr]);
    m = fmaxf(m, __shfl_xor(m, 1));
    m = fmaxf(m, __shfl_xor(m, 2));
    m = fmaxf(m, __shfl_xor(m, 4));
    m = fmaxf(m, __shfl_xor(m, 8));
    mx[rr] = m;
  }
  #pragma unroll
  for (int nt = 0; nt < 13; ++nt)
    #pragma unroll
    for (int rr = 0; rr < 4; ++rr)
      s[nt][rr] = __expf(s[nt][rr] - mx[rr]);
  #pragma unroll
  for (int rr = 0; rr < 4; ++rr) {
    float d = 0.f;
    #pragma unroll
    for (int nt = 0; nt < 13; ++nt) d += s[nt][rr];
    d += __shfl_xor(d, 1);
    d += __shfl_xor(d, 2);
    d += __shfl_xor(d, 4);
    d += __shfl_xor(d, 8);
    dn[rr] = 1.f / d;
  }
  #pragma unroll
  for (int nt = 0; nt < 13; ++nt)
    #pragma unroll
    for (int rr = 0; rr < 4; ++rr)
      pr[w][(lane >> 4) * 4 + rr][nt * 16 + colbase] = (__bf16)(s[nt][rr] * dn[rr]);
  __syncthreads();

  // PV: A = pr[w] (LDS), B = prefetched registers
  f32x4 c4[4] = {};
  __builtin_amdgcn_s_setprio(1);
  #pragma unroll
  for (int kc = 0; kc < 7; ++kc) {
    bf16x8 ap = *(const bf16x8*)&pr[w][lane & 15][kc * 32 + (lane >> 4) * 8];
    #pragma unroll
    for (int dt = 0; dt < 4; ++dt)
      c4[dt] = MFMA16(ap, bvf[dt][kc], c4[dt]);
  }
  __builtin_amdgcn_s_setprio(0);

  // probs-mean: 448 threads x (row, 8-col chunk), vectorized LDS reads
  {
    if (tid < 448) {
      const int row = tid / 28, ch = tid % 28, c0 = ch * 8;
      const int qrow = row0 + row;
      if (qrow < LL && c0 < LL) {
        float sm[8] = {};
        #pragma unroll
        for (int ww = 0; ww < 8; ++ww) {
          bf16x8 v = *(const bf16x8*)&pr[ww][row][c0];
          #pragma unroll
          for (int j = 0; j < 8; ++j) sm[j] += (float)v[j];
        }
        float* dst = &probs_out[((size_t)bb * LL + qrow) * LL + c0];
        if (c0 + 8 <= LL) {
          *(float4*)dst       = make_float4(sm[0] * 0.125f, sm[1] * 0.125f, sm[2] * 0.125f, sm[3] * 0.125f);
          *(float4*)(dst + 4) = make_float4(sm[4] * 0.125f, sm[5] * 0.125f, sm[6] * 0.125f, sm[7] * 0.125f);
        } else {
          #pragma unroll
          for (int j = 0; j < 8; ++j)
            if (c0 + j < LL) dst[j] = sm[j] * 0.125f;
        }
      }
    }
  }
  __syncthreads();   // all pr reads done; smem can be reused as ctile

  // scatter c4 into the f32 ctx tile
  #pragma unroll
  for (int dt = 0; dt < 4; ++dt)
    #pragma unroll
    for (int rr = 0; rr < 4; ++rr)
      ctile[(lane >> 4) * 4 + rr][h * DHH + dt * 16 + (lane & 15)] = c4[dt][rr];
  __syncthreads();

  // fused residual + LayerNorm: wave w handles rows 2w, 2w+1
  #pragma unroll
  for (int rsel = 0; rsel < 2; ++rsel) {
    const int r = w * 2 + rsel;
    const int qrow = row0 + r;
    if (qrow >= LL) continue;
    const int c = lane * 8;
    const float* rrow = resid + (size_t)(bb * LL + qrow) * DD;
    float4 a0 = *(const float4*)&ctile[r][c];
    float4 a1 = *(const float4*)&ctile[r][c + 4];
    float4 b0 = *(const float4*)(rrow + c);
    float4 b1 = *(const float4*)(rrow + c + 4);
    float v[8] = {a0.x + b0.x, a0.y + b0.y, a0.z + b0.z, a0.w + b0.w,
                  a1.x + b1.x, a1.y + b1.y, a1.z + b1.z, a1.w + b1.w};
    float sum = 0.f;
    #pragma unroll
    for (int j = 0; j < 8; ++j) sum += v[j];
    #pragma unroll
    for (int o = 1; o < 64; o <<= 1) sum += __shfl_xor(sum, o);
    const float mu = sum * (1.f / (float)DD);
    float var = 0.f;
    #pragma unroll
    for (int j = 0; j < 8; ++j) { float d = v[j] - mu; var += d * d; }
    #pragma unroll
    for (int o = 1; o < 64; o <<= 1) var += __shfl_xor(var, o);
    const float rstd = rsqrtf(var * (1.f / (float)DD) + 1e-6f);
    float4 g0 = *(const float4*)(gamma + c);
    float4 g1 = *(const float4*)(gamma + c + 4);
    float4 e0 = *(const float4*)(beta + c);
    float4 e1 = *(const float4*)(beta + c + 4);
    float g[8] = {g0.x, g0.y, g0.z, g0.w, g1.x, g1.y, g1.z, g1.w};
    float e[8] = {e0.x, e0.y, e0.z, e0.w, e1.x, e1.y, e1.z, e1.w};
    float o_[8];
    #pragma unroll
    for (int j = 0; j < 8; ++j) o_[j] = (v[j] - mu) * rstd * g[j] + e[j];
    float* orow = out_ctx + (size_t)(bb * LL + qrow) * DD;
    *(float4*)(orow + c)     = make_float4(o_[0], o_[1], o_[2], o_[3]);
    *(float4*)(orow + c + 4) = make_float4(o_[4], o_[5], o_[6], o_[7]);
  }

  // merged finish: blocks strip<8, waves 0-3 fold one (a,b) pair each
  if (strip < 8 && w < 4) {
    const int a = bb, b = strip * 4 + w;
    float s2 = 0.f;
    #pragma unroll
    for (int k = 0; k < 4; ++k) {
      const int l = lane + k * 64;
      if (l < LL) {
        s2 += unkey(rmax[(size_t)b * BL + a * LL + l]);
        s2 += unkey(cmax[(size_t)a * BL + b * LL + l]);
      }
    }
    #pragma unroll
    for (int o = 1; o < 64; o <<= 1) s2 += __shfl_xor(s2, o);
    if (lane == 0)
      out_logits[a * BB + b] = expf(ls[0]) * s2 * (0.5f / (float)LL);
  }
}

// ---------------------------------------------------------------------------
extern "C" void kernel_launch(void* const* d_in, const int* in_sizes, int n_in,
                              void* d_out, int out_size, void* d_ws, size_t ws_size,
                              hipStream_t stream)
{
  const float* xq    = (const float*)d_in[0];
  const float* xk    = (const float*)d_in[1];
  const float* xv    = (const float*)d_in[2];
  const float* Wq    = (const float*)d_in[3];
  const float* bq    = (const float*)d_in[4];
  const float* Wk    = (const float*)d_in[5];
  const float* bk    = (const float*)d_in[6];
  const float* Wv    = (const float*)d_in[7];
  const float* bv    = (const float*)d_in[8];
  const float* gamma = (const float*)d_in[9];
  const float* beta  = (const float*)d_in[10];
  const float* ls    = (const float*)d_in[11];

  float* out_ctx    = (float*)d_out;
  float* out_logits = out_ctx + (size_t)BL * DD;
  float* out_probs  = out_logits + BB * BB;

  const size_t xsz = (size_t)BL * DD;   // 3,211,264
  const size_t wsz = (size_t)DD * DD;   // 262,144
  __bf16* xb = (__bf16*)d_ws;           // 3 * xsz
  __bf16* wb = xb + 3 * xsz;            // 3 * wsz
  __bf16* qp = wb + 3 * wsz;
  __bf16* kp = qp + xsz;
  __bf16* vp = kp + xsz;
  // xb region is dead after proj_gemm: reuse it for vpT and rmax/cmax
  __bf16* vpT = xb;                                  // 16384 * 224 bf16
  unsigned* rmax = (unsigned*)(xb + 3670016);        // 6272*32 u32
  unsigned* cmax = rmax + (size_t)BB * BL;

  cvt_kernel<<<dim3(1696, 3), 256, 0, stream>>>(xq, xk, xv, Wq, Wk, Wv, xb, wb);

  proj_gemm_kernel<<<dim3(49, 4, 3), 256, 0, stream>>>(xb, wb, bq, bk, bv, qp, kp, vp);

  transpose_v_kernel<<<dim3(BB * HH, 4), 256, 0, stream>>>(vp, vpT);

  hipMemsetAsync(rmax, 0, (size_t)2 * BB * BL * sizeof(unsigned), stream);

  retrieve_kernel<<<2401, 256, 0, stream>>>(qp, kp, rmax, cmax);

  attn_kernel<<<dim3(BB, 13), 512, 0, stream>>>(qp, kp, vpT, xq, gamma, beta,
                                                rmax, cmax, ls,
                                                out_ctx, out_probs, out_logits);
}